// Round 1
// baseline (97.643 us; speedup 1.0000x reference)
//
#include <hip/hip_runtime.h>
#include <hip/hip_cooperative_groups.h>

namespace cg = cooperative_groups;

// Problem constants: B=64, T=1024, D=2, max_lag = T/4 = 256, P = T-1 = 1023.
#define TT 1024
#define DD 2
#define MAXLAG 256

// ---------------- Single fused cooperative kernel ----------------
// grid B (=64), block 1024 (16 waves). Block b owns trajectory b:
//   phase 1: stage traj[b] (8 KB) to LDS.
//   phase 2: thread t -> (lag = (t&255)+1, p-slice = t>>8 of 256 positions).
//            s2[p] is wave-uniform (LDS broadcast); s2[p+lag] is
//            lane-consecutive float2 (2-way aliasing = free).
//            Waves are slice-balanced across SIMDs (wave w -> SIMD w%4),
//            so each SIMD gets one wave of each slice length.
//   phase 3: threads 0..255 do the log-log fit (same math as before:
//            sq_err = (intercept - resid)^2).
//   phase 4: ws[b] = per_traj (agent-scope store), grid.sync(),
//            block 0 reduces the 64 scalars and writes the mean.
// No finish counter => nothing in workspace needs pre-zeroing => no
// second dispatch.
__global__ __launch_bounds__(1024) void fused_kernel(const float* __restrict__ alpha_pred,
                                                     const float* __restrict__ traj,
                                                     const int* __restrict__ lengths,
                                                     float* __restrict__ ws,
                                                     float* __restrict__ out) {
    __shared__ float s[TT * DD];           // 8 KB trajectory row
    __shared__ float sums[4 * MAXLAG];     // 4 KB per-slice lag partials
    __shared__ float sr[4], sm[4], ss[4];

    const int b = blockIdx.x;
    const int t = threadIdx.x;

    // ---- stage trajectory row to LDS (512 float4) ----
    const float4* t4 = (const float4*)(traj + (size_t)b * TT * DD);
    float4* s4 = (float4*)s;
    if (t < TT * DD / 4) s4[t] = t4[t];
    __syncthreads();

    const int L = lengths[b];
    const int lagIdx = t & (MAXLAG - 1);
    const int lag = lagIdx + 1;            // 1..256
    const int slice = t >> 8;              // 0..3
    const int cnt = L - lag;               // valid p in [0, cnt)
    const int p0 = slice * 256;
    const int p1 = p0 + 256;
    const int pend = (cnt < p1) ? cnt : p1;

    // Loop runs only valid p (p < L-lag), so p+lag <= L-1 <= 1023: no clamp.
    const float2* s2 = (const float2*)s;
    float acc = 0.0f;
    #pragma unroll 4
    for (int p = p0; p < pend; ++p) {
        float2 a = s2[p];                  // wave-uniform -> broadcast
        float2 e = s2[p + lag];            // lane-consecutive float2
        float dx = e.x - a.x;
        float dy = e.y - a.y;
        acc += dx * dx + dy * dy;
    }
    sums[slice * MAXLAG + lagIdx] = acc;
    __syncthreads();

    // ---- fit on threads 0..255 (waves 0..3); block-level barriers only ----
    float resid = 0.0f, mask = 0.0f, denom = 1.0f;
    if (t < MAXLAG) {
        const float tot = sums[t] + sums[MAXLAG + t]
                        + sums[2 * MAXLAG + t] + sums[3 * MAXLAG + t];
        const float cntf = fmaxf((float)(L - lag), 1.0f);
        const float msd = tot / cntf;
        mask = (L > lag) ? 1.0f : 0.0f;
        resid = logf(msd + 1e-8f) - alpha_pred[b] * logf((float)lag);

        float r = resid * mask, mk = mask;
        for (int off = 32; off; off >>= 1) {
            r  += __shfl_down(r,  off, 64);
            mk += __shfl_down(mk, off, 64);
        }
        if ((t & 63) == 0) { sr[t >> 6] = r; sm[t >> 6] = mk; }
    }
    __syncthreads();

    if (t < MAXLAG) {
        const float sumr = sr[0] + sr[1] + sr[2] + sr[3];
        const float summ = sm[0] + sm[1] + sm[2] + sm[3];
        denom = fmaxf(summ, 1.0f);
        const float intercept = sumr / denom;
        // sq_err = (alpha*log_lag + intercept - log_msd)^2 = (intercept - resid)^2
        const float d = intercept - resid;
        float se = d * d * mask;
        for (int off = 32; off; off >>= 1) se += __shfl_down(se, off, 64);
        if ((t & 63) == 0) ss[t >> 6] = se;
    }
    __syncthreads();

    if (t == 0) {
        const float per_traj = (ss[0] + ss[1] + ss[2] + ss[3]) / denom;
        // agent-scope store: per-XCD L2s are not cross-coherent
        __hip_atomic_store(&ws[b], per_traj, __ATOMIC_RELAXED, __HIP_MEMORY_SCOPE_AGENT);
    }

    cg::this_grid().sync();

    // ---- block 0: mean over B trajectories ----
    if (b == 0 && t < 64) {
        float v = (t < (int)gridDim.x)
                    ? __hip_atomic_load(&ws[t], __ATOMIC_RELAXED, __HIP_MEMORY_SCOPE_AGENT)
                    : 0.0f;
        for (int off = 32; off; off >>= 1) v += __shfl_down(v, off, 64);
        if (t == 0) out[0] = v / (float)gridDim.x;
    }
}

extern "C" void kernel_launch(void* const* d_in, const int* in_sizes, int n_in,
                              void* d_out, int out_size, void* d_ws, size_t ws_size,
                              hipStream_t stream) {
    const float* alpha = (const float*)d_in[0];
    const float* traj  = (const float*)d_in[1];
    const int*   lens  = (const int*)d_in[2];
    float* out = (float*)d_out;
    float* ws  = (float*)d_ws;                 // 64 floats used

    const int B = in_sizes[0];                 // 64

    void* args[] = { (void*)&alpha, (void*)&traj, (void*)&lens, (void*)&ws, (void*)&out };
    hipLaunchCooperativeKernel((void*)fused_kernel, dim3(B), dim3(1024), args, 0, stream);
}